// Round 8
// baseline (218.727 us; speedup 1.0000x reference)
//
#include <hip/hip_runtime.h>

// SelfAttention: B=4, T=2048, C=D=1024, causal, single head. bf16 MFMA.
// ws (MB): [0 Qb 16][16 Kb 16][32 Vtb 16][48 xb 16][64 Wcat 6][70 S bf16 32][134 P 32]
// R8: (1) gemm template now true double-buffered 2-phase: stage(next) ->
// vmcnt(8) [retires prev-iter loads, latency hidden under compute] -> raw
// s_barrier -> compute -> lgkmcnt(0) -> raw s_barrier. No __syncthreads in
// the loop (would drain prefetch). (2) qkv blocks XCD-panel-swizzled so the
// 8 blocks sharing an operand panel land on one XCD L2 (fetch 150MB -> ~60).

using u16 = unsigned short;
typedef __attribute__((ext_vector_type(8))) short short8;
typedef __attribute__((ext_vector_type(4))) float f32x4;

__device__ __forceinline__ u16 f2b(float f) {
  unsigned u = __builtin_bit_cast(unsigned, f);
  u += 0x7fffu + ((u >> 16) & 1u);
  return (u16)(u >> 16);
}

__device__ __forceinline__ float b2f(u16 h) {
  return __builtin_bit_cast(float, (unsigned)h << 16);
}

__device__ __forceinline__ void async16(void* lds, const void* g) {
  __builtin_amdgcn_global_load_lds(
      (const __attribute__((address_space(1))) unsigned int*)g,
      (__attribute__((address_space(3))) unsigned int*)lds, 16, 0, 0);
}

// one launch: x (8192x1024) + Wq,Wk,Wv (1024x1024 each) -> bf16
__global__ __launch_bounds__(256) void cvt_all_kernel(
    const float* __restrict__ x, const float* __restrict__ Wq,
    const float* __restrict__ Wk, const float* __restrict__ Wv,
    u16* __restrict__ xb, u16* __restrict__ Wcat) {
  const int i = blockIdx.x * 256 + threadIdx.x;  // float4 chunk index
  const float* src;
  u16* dst;
  int c;
  if (i < 2097152) {  // 8192*1024/4
    src = x; dst = xb; c = i;
  } else {
    const int r = i - 2097152;
    const int seg = r >> 18;  // 262144 chunks per W
    src = seg == 0 ? Wq : (seg == 1 ? Wk : Wv);
    dst = Wcat + (size_t)seg * 1048576;
    c = r & 262143;
  }
  const float4 v = reinterpret_cast<const float4*>(src)[c];
  ushort4 o;
  o.x = f2b(v.x); o.y = f2b(v.y); o.z = f2b(v.z); o.w = f2b(v.w);
  reinterpret_cast<ushort4*>(dst)[c] = o;
}

// C[m][n] = sum_k A[m][k]*B[n][k]; 128x128 tile, BK=64, 4 waves (2x2 of 64x64),
// double-buffered. LDS rows 128B, 16B-slot s of row r at phys slot s^(r&7);
// global source pre-inverse-swizzled (rule 21): conflict-free frag reads.
// A-frag: row=lane&15, k=8*(lane>>4)+j+32*kk ; D-frag: col=lane&15,
// row=4*(lane>>4)+rr (HW-verified m89/m91).
template <typename Epi>
__device__ __forceinline__ void gemm_bt_tile(const u16* __restrict__ A, int lda,
                                             const u16* __restrict__ B, int ldb,
                                             int nt, Epi&& epi) {
  __shared__ __align__(16) u16 As[2][128 * 64];
  __shared__ __align__(16) u16 Bs[2][128 * 64];
  const int tid = threadIdx.x;
  const int lane = tid & 63;
  const int w = tid >> 6;
  const int wr = (w >> 1) << 6;
  const int wc = (w & 1) << 6;

  f32x4 acc[4][4];
#pragma unroll
  for (int i = 0; i < 4; ++i)
#pragma unroll
    for (int j = 0; j < 4; ++j) acc[i][j] = f32x4{0.f, 0.f, 0.f, 0.f};

  // staging: thread t -> rows (t>>3) + 32*s, phys 16B-slot t&7,
  // logical col ((t&7)^(row&7))*8  (row&7 invariant across s since 32%8==0)
  const int sr = tid >> 3;
  const int ce = ((tid & 7) ^ (sr & 7)) << 3;
  const u16* gA = A + (size_t)sr * lda + ce;
  const u16* gB = B + (size_t)sr * ldb + ce;

  const int hi = lane >> 4;
  const int lo7 = lane & 7;
  const int ra = (wr + (lane & 15)) << 6;  // *64
  const int rb = (wc + (lane & 15)) << 6;
  const int sk0 = (hi ^ lo7) << 3;
  const int sk1 = ((4 + hi) ^ lo7) << 3;

  auto stage = [&](int buf, int t) {
    u16* const dA = As[buf] + tid * 8;
    u16* const dB = Bs[buf] + tid * 8;
    const u16* ga = gA + t * 64;
    const u16* gb = gB + t * 64;
#pragma unroll
    for (int s = 0; s < 4; ++s) {
      async16(dA + s * 2048, ga + (size_t)(s * 32) * lda);
      async16(dB + s * 2048, gb + (size_t)(s * 32) * ldb);
    }
  };

  auto compute = [&](int buf) {
    const u16* const Ab = As[buf];
    const u16* const Bb = Bs[buf];
#pragma unroll
    for (int kk = 0; kk < 2; ++kk) {
      const int sk = kk ? sk1 : sk0;
      short8 af[4], bf[4];
#pragma unroll
      for (int i = 0; i < 4; ++i)
        af[i] = *(const short8*)(Ab + ra + i * 1024 + sk);
#pragma unroll
      for (int j = 0; j < 4; ++j)
        bf[j] = *(const short8*)(Bb + rb + j * 1024 + sk);
#pragma unroll
      for (int i = 0; i < 4; ++i)
#pragma unroll
        for (int j = 0; j < 4; ++j)
          acc[i][j] = __builtin_amdgcn_mfma_f32_16x16x32_bf16(af[i], bf[j],
                                                              acc[i][j], 0, 0, 0);
    }
  };

  stage(0, 0);
  int cur = 0;
  for (int t = 0; t < nt - 1; ++t) {
    stage(cur ^ 1, t + 1);  // 8 more in flight (16 total)
    asm volatile("s_waitcnt vmcnt(8)" ::: "memory");  // cur tile landed
    __builtin_amdgcn_s_barrier();                     // ..for ALL waves
    compute(cur);
    asm volatile("s_waitcnt lgkmcnt(0)" ::: "memory");  // reads retired
    __builtin_amdgcn_s_barrier();  // safe to overwrite cur next iter
    cur ^= 1;
  }
  asm volatile("s_waitcnt vmcnt(0)" ::: "memory");
  __builtin_amdgcn_s_barrier();
  compute(cur);
  epi(acc, wr, wc, lane);
}

// QKV, XCD-panel-swizzled: xcd=bid&7 gets 24 panels; panel<128 -> (z,mt) Q/K
// row-panel (8 nt units); panel>=128 -> V, grouped by x col-block nt (8 mt).
__global__ __launch_bounds__(256) void qkv_kernel(
    const u16* __restrict__ xb, const u16* __restrict__ Wcat,
    const float* __restrict__ bq, const float* __restrict__ bk,
    const float* __restrict__ bv, u16* __restrict__ Qb, u16* __restrict__ Kb,
    u16* __restrict__ Vtb) {
  const int bid = blockIdx.x;
  const int xcd = bid & 7;
  const int u = bid >> 3;                  // 0..191
  const int panel = xcd * 24 + (u >> 3);   // 0..191 (bijective)
  const int unit = u & 7;
  if (panel < 128) {
    const int z = panel >> 6;      // 0:Q 1:K
    const int mt = panel & 63;
    const int nt = unit;
    const u16* W = Wcat + (size_t)z * 1048576;
    const float* bias = z ? bk : bq;
    u16* out = z ? Kb : Qb;
    const float scale = z ? 1.0f : 0.03125f;  // Q pre-scaled by 1/sqrt(1024)
    gemm_bt_tile(
        xb + (size_t)mt * 128 * 1024, 1024, W + (size_t)nt * 128 * 1024, 1024, 16,
        [&](f32x4(&acc)[4][4], int wr, int wc, int lane) {
          const int r0 = mt * 128 + wr + ((lane >> 4) << 2);
          const int c0 = nt * 128 + wc + (lane & 15);
#pragma unroll
          for (int i = 0; i < 4; ++i)
#pragma unroll
            for (int j = 0; j < 4; ++j) {
              const int col = c0 + j * 16;
              const float bb = bias[col];
#pragma unroll
              for (int rr = 0; rr < 4; ++rr)
                out[(size_t)(r0 + i * 16 + rr) * 1024 + col] =
                    f2b((acc[i][j][rr] + bb) * scale);
            }
        });
  } else {
    const int nt = panel - 128;  // x col-block (B-panel, shared by 8 units)
    const int mt = unit;         // Wv row-block
    const u16* Wvb = Wcat + (size_t)2 * 1048576;
    gemm_bt_tile(
        Wvb + (size_t)mt * 128 * 1024, 1024, xb + (size_t)nt * 128 * 1024, 1024, 16,
        [&](f32x4(&acc)[4][4], int wr, int wc, int lane) {
          const int r0 = mt * 128 + wr + ((lane >> 4) << 2);
          const int c0 = nt * 128 + wc + (lane & 15);
#pragma unroll
          for (int i = 0; i < 4; ++i)
#pragma unroll
            for (int rr = 0; rr < 4; ++rr) {
              const int row = r0 + i * 16 + rr;  // d index
              const float bb = bv[row];
#pragma unroll
              for (int j = 0; j < 4; ++j)
                Vtb[(size_t)row * 8192 + c0 + j * 16] = f2b(acc[i][j][rr] + bb);
            }
        });
  }
}

// lower-triangle tiles only: grid (136, 4); S stored bf16
__global__ __launch_bounds__(256) void score_kernel(const u16* __restrict__ Qb,
                                                    const u16* __restrict__ Kb,
                                                    u16* __restrict__ S) {
  const int b = blockIdx.y;
  const int t = blockIdx.x;
  int qt = 0;
  while ((qt + 1) * (qt + 2) / 2 <= t) ++qt;
  const int kt = t - (qt * (qt + 1)) / 2;
  const u16* A = Qb + ((size_t)b * 2048 + qt * 128) * 1024;
  const u16* Bp = Kb + ((size_t)b * 2048 + kt * 128) * 1024;
  u16* Sb = S + (size_t)b * 2048 * 2048;
  gemm_bt_tile(A, 1024, Bp, 1024, 16,
               [&](f32x4(&acc)[4][4], int wr, int wc, int lane) {
                 const int r0 = qt * 128 + wr + ((lane >> 4) << 2);
                 const int c0 = kt * 128 + wc + (lane & 15);
#pragma unroll
                 for (int i = 0; i < 4; ++i)
#pragma unroll
                   for (int j = 0; j < 4; ++j)
#pragma unroll
                     for (int rr = 0; rr < 4; ++rr)
                       Sb[(size_t)(r0 + i * 16 + rr) * 2048 + c0 + j * 16] =
                           f2b(acc[i][j][rr]);
               });
}

// one block per row; bf16 S in, bf16 P out; fully short8-vectorized.
__global__ __launch_bounds__(256) void softmax_kernel(const u16* __restrict__ S,
                                                      u16* __restrict__ P) {
  __shared__ float redm[4], reds[4];
  const int rowid = blockIdx.x;
  const int b = rowid >> 11;
  const int q = rowid & 2047;
  const u16* Srow = S + ((size_t)b * 2048 + q) * 2048;
  u16* Prow = P + ((size_t)b * 2048 + q) * 2048;
  const int L = q + 1;
  const int Lpad = ((q >> 7) + 1) << 7;
  const int tid = threadIdx.x;
  const int k0 = tid << 3;
  const bool active = k0 < Lpad;
  float v[8];
  float m = -1e30f;
  if (active) {
    const short8 s8 = *(const short8*)(Srow + k0);
#pragma unroll
    for (int j = 0; j < 8; ++j) {
      v[j] = (k0 + j < L) ? b2f((u16)s8[j]) : -1e30f;
      m = fmaxf(m, v[j]);
    }
  }
#pragma unroll
  for (int o = 32; o > 0; o >>= 1) m = fmaxf(m, __shfl_xor(m, o));
  if ((tid & 63) == 0) redm[tid >> 6] = m;
  __syncthreads();
  m = fmaxf(fmaxf(redm[0], redm[1]), fmaxf(redm[2], redm[3]));
  float s = 0.f;
  if (active) {
#pragma unroll
    for (int j = 0; j < 8; ++j) {
      const float e = (k0 + j < L) ? __expf(v[j] - m) : 0.f;
      v[j] = e;
      s += e;
    }
  }
#pragma unroll
  for (int o = 32; o > 0; o >>= 1) s += __shfl_xor(s, o);
  if ((tid & 63) == 0) reds[tid >> 6] = s;
  __syncthreads();
  s = reds[0] + reds[1] + reds[2] + reds[3];
  const float inv = 1.0f / s;
  if (active) {
    short8 o8;
#pragma unroll
    for (int j = 0; j < 8; ++j)
      o8[j] = (short)((k0 + j < L) ? f2b(v[j] * inv) : (u16)0);
    *(short8*)(Prow + k0) = o8;
  }
}

// O = P @ V using Vt[d][t]; K-loop truncated by causality; balanced grid.
__global__ __launch_bounds__(256) void pv_kernel(const u16* __restrict__ P,
                                                 const u16* __restrict__ Vtb,
                                                 float* __restrict__ O) {
  const int bid = blockIdx.x;  // 512
  const int pair = bid >> 8;
  const int idx = bid & 255;
  const int hb = idx >> 7;
  const int qt_raw = (idx >> 3) & 15;
  const int dt = idx & 7;
  const int qt = pair ? (15 - qt_raw) : qt_raw;
  const int b = pair * 2 + hb;
  const u16* A = P + (size_t)b * 2048 * 2048 + (size_t)qt * 128 * 2048;
  const u16* Bp = Vtb + (size_t)dt * 128 * 8192 + b * 2048;
  float* Ob = O + (size_t)b * 2048 * 1024;
  gemm_bt_tile(A, 2048, Bp, 8192, (qt + 1) * 2,
               [&](f32x4(&acc)[4][4], int wr, int wc, int lane) {
                 const int r0 = qt * 128 + wr + ((lane >> 4) << 2);
                 const int c0 = dt * 128 + wc + (lane & 15);
#pragma unroll
                 for (int i = 0; i < 4; ++i)
#pragma unroll
                   for (int j = 0; j < 4; ++j)
#pragma unroll
                     for (int rr = 0; rr < 4; ++rr)
                       Ob[(size_t)(r0 + i * 16 + rr) * 1024 + c0 + j * 16] =
                           acc[i][j][rr];
               });
}

extern "C" void kernel_launch(void* const* d_in, const int* in_sizes, int n_in,
                              void* d_out, int out_size, void* d_ws, size_t ws_size,
                              hipStream_t stream) {
  const float* x = (const float*)d_in[0];
  const float* Wq = (const float*)d_in[1];
  const float* bq = (const float*)d_in[2];
  const float* Wk = (const float*)d_in[3];
  const float* bk = (const float*)d_in[4];
  const float* Wv = (const float*)d_in[5];
  const float* bv = (const float*)d_in[6];
  float* out = (float*)d_out;
  char* ws = (char*)d_ws;
  u16* Qb = (u16*)(ws);
  u16* Kb = (u16*)(ws + (16u << 20));
  u16* Vtb = (u16*)(ws + (32u << 20));
  u16* xb = (u16*)(ws + (48u << 20));
  u16* Wcat = (u16*)(ws + (64u << 20));
  u16* S = (u16*)(ws + (70u << 20));
  u16* P = (u16*)(ws + (134u << 20));

  cvt_all_kernel<<<11264, 256, 0, stream>>>(x, Wq, Wk, Wv, xb, Wcat);
  qkv_kernel<<<1536, 256, 0, stream>>>(xb, Wcat, bq, bk, bv, Qb, Kb, Vtb);
  score_kernel<<<dim3(136, 4), 256, 0, stream>>>(Qb, Kb, S);
  softmax_kernel<<<8192, 256, 0, stream>>>(S, P);
  pv_kernel<<<512, 256, 0, stream>>>(P, Vtb, out);
}

// Round 9
// 162.425 us; speedup vs baseline: 1.3466x; 1.3466x over previous
//
#include <hip/hip_runtime.h>

// SelfAttention: B=4, T=2048, C=D=1024, causal, single head. bf16 MFMA.
// ws (MB): [0 Qb 16][16 Kb 16][32 Vtb 16][48 xb 16][64 Wcat 6][70 S bf16 32][134 P 32]
// R9: score/pv reverted to R7 single-buffer template (the 70us-class one).
// Q/K projection moved to a faithful 8-phase 256x256 BK=64 pipeline with the
// ledger-derived counted-vmcnt schedule (vmcnt(6) at phases 4/8 only; 1
// half-tile stage per phase; issue->use distance 6-7 phases). V projection
// stays on the old template as its own kernel (512 blocks).

using u16 = unsigned short;
typedef __attribute__((ext_vector_type(8))) short short8;
typedef __attribute__((ext_vector_type(4))) float f32x4;

__device__ __forceinline__ u16 f2b(float f) {
  unsigned u = __builtin_bit_cast(unsigned, f);
  u += 0x7fffu + ((u >> 16) & 1u);
  return (u16)(u >> 16);
}

__device__ __forceinline__ float b2f(u16 h) {
  return __builtin_bit_cast(float, (unsigned)h << 16);
}

__device__ __forceinline__ void async16(void* lds, const void* g) {
  __builtin_amdgcn_global_load_lds(
      (const __attribute__((address_space(1))) unsigned int*)g,
      (__attribute__((address_space(3))) unsigned int*)lds, 16, 0, 0);
}

__device__ __forceinline__ void block_barrier() {
  asm volatile("" ::: "memory");
  __builtin_amdgcn_s_barrier();
  asm volatile("" ::: "memory");
}

// one launch: x (8192x1024) + Wq,Wk,Wv (1024x1024 each) -> bf16
__global__ __launch_bounds__(256) void cvt_all_kernel(
    const float* __restrict__ x, const float* __restrict__ Wq,
    const float* __restrict__ Wk, const float* __restrict__ Wv,
    u16* __restrict__ xb, u16* __restrict__ Wcat) {
  const int i = blockIdx.x * 256 + threadIdx.x;
  const float* src;
  u16* dst;
  int c;
  if (i < 2097152) {
    src = x; dst = xb; c = i;
  } else {
    const int r = i - 2097152;
    const int seg = r >> 18;
    src = seg == 0 ? Wq : (seg == 1 ? Wk : Wv);
    dst = Wcat + (size_t)seg * 1048576;
    c = r & 262143;
  }
  const float4 v = reinterpret_cast<const float4*>(src)[c];
  ushort4 o;
  o.x = f2b(v.x); o.y = f2b(v.y); o.z = f2b(v.z); o.w = f2b(v.w);
  reinterpret_cast<ushort4*>(dst)[c] = o;
}

// =================== 8-phase 256x256 BK=64 pipelined NT-GEMM ===============
// C[256][256] = A[256xK]*B[256xK]^T. 8 waves (2Mx4N), per-wave 128x64 out.
// LDS: [buf(=ktile&1)][half][128x64] for A and B (128 KiB total).
// A halves: E = rows {0-63,128-191}, L = {64-127,192-255}.
// B halves: E = rows {r:(r>>5)&1==0}, L = rest (per-wave 32-col split).
// Swizzle: 16B-slot s of LDS row r at phys s^(r&7); inverse on global src.
// Ledger: prologue 7 halves (14 loads), vmcnt(6) => t0 landed. Each phase
// stages 1 half; vmcnt(6)@ph4 retires t+1's 4 halves, @ph8 retires t+2's.
// Every LDS half overwritten >=1 barrier-pair after its last ds_read.
#define STG_A(buf, half, roff, ku)                                          \
  {                                                                         \
    async16(&Asm[buf][half][tid * 8], gA0 + (size_t)(roff)*lda + (ku));     \
    async16(&Asm[buf][half][4096 + tid * 8],                                \
            gA0 + (size_t)((roff) + 128) * lda + (ku));                     \
  }
#define STG_B(buf, half, roff, ku)                                          \
  {                                                                         \
    async16(&Bsm[buf][half][tid * 8], gB0 + (size_t)(roff)*ldb + (ku));     \
    async16(&Bsm[buf][half][4096 + tid * 8],                                \
            gB0 + (size_t)((roff) + 128) * ldb + (ku));                     \
  }
#define RD_A(buf, hh)                                                       \
  {                                                                         \
    _Pragma("unroll") for (int ii = 0; ii < 4; ++ii) {                      \
      a[ii][0] = *(const short8*)(&Asm[buf][hh][aoff + ii * 1024 + sk0]);   \
      a[ii][1] = *(const short8*)(&Asm[buf][hh][aoff + ii * 1024 + sk1]);   \
    }                                                                       \
  }
#define RD_B(buf, cc, breg)                                                 \
  {                                                                         \
    _Pragma("unroll") for (int jj = 0; jj < 2; ++jj) {                      \
      breg[jj][0] = *(const short8*)(&Bsm[buf][cc][boff + jj * 1024 + sk0]);\
      breg[jj][1] = *(const short8*)(&Bsm[buf][cc][boff + jj * 1024 + sk1]);\
    }                                                                       \
  }
#define QUAD(hh, cc, breg)                                                  \
  {                                                                         \
    __builtin_amdgcn_s_setprio(1);                                          \
    _Pragma("unroll") for (int ii = 0; ii < 4; ++ii)                        \
        _Pragma("unroll") for (int jj = 0; jj < 2; ++jj) {                  \
      acc[(hh)*4 + ii][(cc)*2 + jj] =                                       \
          __builtin_amdgcn_mfma_f32_16x16x32_bf16(                          \
              a[ii][0], breg[jj][0], acc[(hh)*4 + ii][(cc)*2 + jj], 0,0,0); \
      acc[(hh)*4 + ii][(cc)*2 + jj] =                                       \
          __builtin_amdgcn_mfma_f32_16x16x32_bf16(                          \
              a[ii][1], breg[jj][1], acc[(hh)*4 + ii][(cc)*2 + jj], 0,0,0); \
    }                                                                       \
    __builtin_amdgcn_s_setprio(0);                                          \
  }
#define LGK0 asm volatile("s_waitcnt lgkmcnt(0)" ::: "memory")
#define VM6 asm volatile("s_waitcnt vmcnt(6)" ::: "memory")

template <int NT, typename Epi>
__device__ __forceinline__ void gemm256_8ph(const u16* __restrict__ A, int lda,
                                            const u16* __restrict__ B, int ldb,
                                            Epi&& epi) {
  __shared__ __align__(16) u16 Asm[2][2][8192];
  __shared__ __align__(16) u16 Bsm[2][2][8192];
  const int tid = threadIdx.x;  // 0..511
  const int lane = tid & 63;
  const int w = tid >> 6;
  const int wm = w >> 2;  // 0..1
  const int wn = w & 3;   // 0..3

  f32x4 acc[8][4];
#pragma unroll
  for (int i = 0; i < 8; ++i)
#pragma unroll
    for (int j = 0; j < 4; ++j) acc[i][j] = f32x4{0.f, 0.f, 0.f, 0.f};

  // staging: thread -> LDS row sr (load0) / sr+64 (load1), phys slot tid&7
  const int sr = tid >> 3;
  const int ce = ((tid & 7) ^ (sr & 7)) << 3;  // inverse-swizzled global col
  const u16* gA0 = A + (size_t)sr * lda + ce;
  const int bE = (sr & 31) + ((sr >> 5) << 6);
  const u16* gB0 = B + (size_t)bE * ldb + ce;

  // fragment read offsets
  const int l15 = lane & 15;
  const int hi = lane >> 4;
  const int lo7 = lane & 7;
  const int aoff = wm * 4096 + l15 * 64;
  const int boff = wn * 2048 + l15 * 64;
  const int sk0 = (hi ^ lo7) << 3;
  const int sk1 = ((4 + hi) ^ lo7) << 3;

  short8 a[4][2], bEr[2][2], bLr[2][2];

  // prologue: t0 all 4 halves + t1 {AE,BE,AL}  (14 loads)
  STG_A(0, 0, 0, 0); STG_B(0, 0, 0, 0); STG_A(0, 1, 64, 0); STG_B(0, 1, 32, 0);
  STG_A(1, 0, 0, 64); STG_B(1, 0, 0, 64); STG_A(1, 1, 64, 64);
  VM6;  // retire 8 oldest = t0 fully landed
  block_barrier();

  for (int t = 0; t < NT; t += 2) {
    const int k1 = (t + 1) * 64;
    const int t2c = (t + 2 < NT) ? (t + 2) : (NT - 1);
    const int t3c = (t + 3 < NT) ? (t + 3) : (NT - 1);
    const int k2 = t2c * 64;
    const int k3 = t3c * 64;
    // ph1: quad (A-E x B-E) of tile t (buf0); stage (t+1).BL
    RD_A(0, 0); RD_B(0, 0, bEr); STG_B(1, 1, 32, k1);
    block_barrier(); LGK0; QUAD(0, 0, bEr); block_barrier();
    // ph2: quad (A-E x B-L); stage (t+2).AE
    RD_B(0, 1, bLr); STG_A(0, 0, 0, k2);
    block_barrier(); LGK0; QUAD(0, 1, bLr); block_barrier();
    // ph3: quad (A-L x B-L); stage (t+2).BE
    RD_A(0, 1); STG_B(0, 0, 0, k2);
    block_barrier(); LGK0; QUAD(1, 1, bLr); block_barrier();
    // ph4: quad (A-L x B-E, regs held); stage (t+2).AL; t+1 must land
    STG_A(0, 1, 64, k2);
    VM6; block_barrier(); QUAD(1, 0, bEr); block_barrier();
    // ph5: tile t+1 (buf1): quad (A-E x B-E); stage (t+2).BL
    RD_A(1, 0); RD_B(1, 0, bEr); STG_B(0, 1, 32, k2);
    block_barrier(); LGK0; QUAD(0, 0, bEr); block_barrier();
    // ph6: quad (A-E x B-L); stage (t+3).AE
    RD_B(1, 1, bLr); STG_A(1, 0, 0, k3);
    block_barrier(); LGK0; QUAD(0, 1, bLr); block_barrier();
    // ph7: quad (A-L x B-L); stage (t+3).BE
    RD_A(1, 1); STG_B(1, 0, 0, k3);
    block_barrier(); LGK0; QUAD(1, 1, bLr); block_barrier();
    // ph8: quad (A-L x B-E); stage (t+3).AL; t+2 must land
    STG_A(1, 1, 64, k3);
    VM6; block_barrier(); QUAD(1, 0, bEr); block_barrier();
  }
  asm volatile("s_waitcnt vmcnt(0)" ::: "memory");  // drain dangling DMA
  epi(acc, wm, wn, lane);
}

// Q+K projection: A = xb [8192][1024], B = Wcat rows 0..2047; 256 blocks.
// XCD swizzle groups 4 consecutive mt per XCD (x-panel L2 locality).
__global__ __launch_bounds__(512, 1) void qkv_qk_kernel(
    const u16* __restrict__ xb, const u16* __restrict__ Wcat,
    const float* __restrict__ bq, const float* __restrict__ bk,
    u16* __restrict__ Qb, u16* __restrict__ Kb) {
  const int bid = blockIdx.x;
  const int swz = (bid & 7) * 32 + (bid >> 3);  // 256 = 8*32
  const int mt = swz >> 3, nt = swz & 7;
  const int z = nt >> 2;  // 0:Q 1:K
  const float* bias = z ? bk : bq;
  u16* out = z ? Kb : Qb;
  const float scale = z ? 1.0f : 0.03125f;  // Q pre-scaled by 1/sqrt(1024)
  gemm256_8ph<16>(
      xb + (size_t)mt * 256 * 1024, 1024, Wcat + (size_t)nt * 256 * 1024, 1024,
      [&](f32x4(&acc)[8][4], int wm, int wn, int lane) {
        const int r0 = mt * 256 + wm * 128 + ((lane >> 4) << 2);
        const int c0 = (nt & 3) * 256 + wn * 64 + (lane & 15);
#pragma unroll
        for (int i8 = 0; i8 < 8; ++i8) {
          const int rb = r0 + (i8 >> 2) * 64 + (i8 & 3) * 16;
#pragma unroll
          for (int i4 = 0; i4 < 4; ++i4) {
            const int col = c0 + (i4 >> 1) * 32 + (i4 & 1) * 16;
            const float bb = bias[col];
#pragma unroll
            for (int rr = 0; rr < 4; ++rr)
              out[(size_t)(rb + rr) * 1024 + col] =
                  f2b((acc[i8][i4][rr] + bb) * scale);
          }
        }
      });
}

// ============== R7 single-buffer 128x128 BK=64 template (proven) ===========
template <typename Epi>
__device__ __forceinline__ void gemm_bt_tile(const u16* __restrict__ A, int lda,
                                             const u16* __restrict__ B, int ldb,
                                             int nt, Epi&& epi) {
  __shared__ __align__(16) u16 As[128 * 64];
  __shared__ __align__(16) u16 Bs[128 * 64];
  const int tid = threadIdx.x;
  const int lane = tid & 63;
  const int w = tid >> 6;
  const int wr = (w >> 1) << 6;
  const int wc = (w & 1) << 6;

  f32x4 acc[4][4];
#pragma unroll
  for (int i = 0; i < 4; ++i)
#pragma unroll
    for (int j = 0; j < 4; ++j) acc[i][j] = f32x4{0.f, 0.f, 0.f, 0.f};

  const int sr = tid >> 3;
  const int ce = ((tid & 7) ^ (sr & 7)) << 3;
  const u16* gA = A + (size_t)sr * lda + ce;
  const u16* gB = B + (size_t)sr * ldb + ce;
  u16* const dA = As + tid * 8;
  u16* const dB = Bs + tid * 8;

  const int hi = lane >> 4;
  const int lo7 = lane & 7;
  const int ra = (wr + (lane & 15)) << 6;
  const int rb = (wc + (lane & 15)) << 6;
  const int sk0 = (hi ^ lo7) << 3;
  const int sk1 = ((4 + hi) ^ lo7) << 3;

  for (int t = 0; t < nt; ++t) {
    __syncthreads();
#pragma unroll
    for (int s = 0; s < 4; ++s) {
      async16(dA + s * 2048, gA + (size_t)(s * 32) * lda);
      async16(dB + s * 2048, gB + (size_t)(s * 32) * ldb);
    }
    gA += 64;
    gB += 64;
    __syncthreads();
#pragma unroll
    for (int kk = 0; kk < 2; ++kk) {
      const int sk = kk ? sk1 : sk0;
      short8 af[4], bf[4];
#pragma unroll
      for (int i = 0; i < 4; ++i)
        af[i] = *(const short8*)(As + ra + i * 1024 + sk);
#pragma unroll
      for (int j = 0; j < 4; ++j)
        bf[j] = *(const short8*)(Bs + rb + j * 1024 + sk);
#pragma unroll
      for (int i = 0; i < 4; ++i)
#pragma unroll
        for (int j = 0; j < 4; ++j)
          acc[i][j] = __builtin_amdgcn_mfma_f32_16x16x32_bf16(af[i], bf[j],
                                                              acc[i][j], 0, 0, 0);
    }
  }
  epi(acc, wr, wc, lane);
}

// V projection: Vt = Wv @ x^T; 512 blocks (8 mt x 64 nt), nt-grouped per XCD.
__global__ __launch_bounds__(256) void qkv_v_kernel(
    const u16* __restrict__ xb, const u16* __restrict__ Wcat,
    const float* __restrict__ bv, u16* __restrict__ Vtb) {
  const int bid = blockIdx.x;
  const int u = bid >> 3;
  const int nt = (bid & 7) * 8 + (u >> 3);  // x col-block, 8 per XCD
  const int mt = u & 7;                     // Wv row-block
  const u16* Wvb = Wcat + (size_t)2 * 1048576;
  gemm_bt_tile(
      Wvb + (size_t)mt * 128 * 1024, 1024, xb + (size_t)nt * 128 * 1024, 1024, 16,
      [&](f32x4(&acc)[4][4], int wr, int wc, int lane) {
        const int r0 = mt * 128 + wr + ((lane >> 4) << 2);
        const int c0 = nt * 128 + wc + (lane & 15);
#pragma unroll
        for (int i = 0; i < 4; ++i)
#pragma unroll
          for (int rr = 0; rr < 4; ++rr) {
            const int row = r0 + i * 16 + rr;  // d index
            const float bb = bv[row];
#pragma unroll
            for (int j = 0; j < 4; ++j)
              Vtb[(size_t)row * 8192 + c0 + j * 16] = f2b(acc[i][j][rr] + bb);
          }
      });
}

// lower-triangle tiles only: grid (136, 4); S stored bf16
__global__ __launch_bounds__(256) void score_kernel(const u16* __restrict__ Qb,
                                                    const u16* __restrict__ Kb,
                                                    u16* __restrict__ S) {
  const int b = blockIdx.y;
  const int t = blockIdx.x;
  int qt = 0;
  while ((qt + 1) * (qt + 2) / 2 <= t) ++qt;
  const int kt = t - (qt * (qt + 1)) / 2;
  const u16* A = Qb + ((size_t)b * 2048 + qt * 128) * 1024;
  const u16* Bp = Kb + ((size_t)b * 2048 + kt * 128) * 1024;
  u16* Sb = S + (size_t)b * 2048 * 2048;
  gemm_bt_tile(A, 1024, Bp, 1024, 16,
               [&](f32x4(&acc)[4][4], int wr, int wc, int lane) {
                 const int r0 = qt * 128 + wr + ((lane >> 4) << 2);
                 const int c0 = kt * 128 + wc + (lane & 15);
#pragma unroll
                 for (int i = 0; i < 4; ++i)
#pragma unroll
                   for (int j = 0; j < 4; ++j)
#pragma unroll
                     for (int rr = 0; rr < 4; ++rr)
                       Sb[(size_t)(r0 + i * 16 + rr) * 2048 + c0 + j * 16] =
                           f2b(acc[i][j][rr]);
               });
}

// one block per row; bf16 S in, bf16 P out; fully short8-vectorized.
__global__ __launch_bounds__(256) void softmax_kernel(const u16* __restrict__ S,
                                                      u16* __restrict__ P) {
  __shared__ float redm[4], reds[4];
  const int rowid = blockIdx.x;
  const int b = rowid >> 11;
  const int q = rowid & 2047;
  const u16* Srow = S + ((size_t)b * 2048 + q) * 2048;
  u16* Prow = P + ((size_t)b * 2048 + q) * 2048;
  const int L = q + 1;
  const int Lpad = ((q >> 7) + 1) << 7;
  const int tid = threadIdx.x;
  const int k0 = tid << 3;
  const bool active = k0 < Lpad;
  float v[8];
  float m = -1e30f;
  if (active) {
    const short8 s8 = *(const short8*)(Srow + k0);
#pragma unroll
    for (int j = 0; j < 8; ++j) {
      v[j] = (k0 + j < L) ? b2f((u16)s8[j]) : -1e30f;
      m = fmaxf(m, v[j]);
    }
  }
#pragma unroll
  for (int o = 32; o > 0; o >>= 1) m = fmaxf(m, __shfl_xor(m, o));
  if ((tid & 63) == 0) redm[tid >> 6] = m;
  __syncthreads();
  m = fmaxf(fmaxf(redm[0], redm[1]), fmaxf(redm[2], redm[3]));
  float s = 0.f;
  if (active) {
#pragma unroll
    for (int j = 0; j < 8; ++j) {
      const float e = (k0 + j < L) ? __expf(v[j] - m) : 0.f;
      v[j] = e;
      s += e;
    }
  }
#pragma unroll
  for (int o = 32; o > 0; o >>= 1) s += __shfl_xor(s, o);
  if ((tid & 63) == 0) reds[tid >> 6] = s;
  __syncthreads();
  s = reds[0] + reds[1] + reds[2] + reds[3];
  const float inv = 1.0f / s;
  if (active) {
    short8 o8;
#pragma unroll
    for (int j = 0; j < 8; ++j)
      o8[j] = (short)((k0 + j < L) ? f2b(v[j] * inv) : (u16)0);
    *(short8*)(Prow + k0) = o8;
  }
}

// O = P @ V using Vt[d][t]; K-loop truncated by causality; balanced grid.
__global__ __launch_bounds__(256) void pv_kernel(const u16* __restrict__ P,
                                                 const u16* __restrict__ Vtb,
                                                 float* __restrict__ O) {
  const int bid = blockIdx.x;  // 512
  const int pair = bid >> 8;
  const int idx = bid & 255;
  const int hb = idx >> 7;
  const int qt_raw = (idx >> 3) & 15;
  const int dt = idx & 7;
  const int qt = pair ? (15 - qt_raw) : qt_raw;
  const int b = pair * 2 + hb;
  const u16* A = P + (size_t)b * 2048 * 2048 + (size_t)qt * 128 * 2048;
  const u16* Bp = Vtb + (size_t)dt * 128 * 8192 + b * 2048;
  float* Ob = O + (size_t)b * 2048 * 1024;
  gemm_bt_tile(A, 2048, Bp, 8192, (qt + 1) * 2,
               [&](f32x4(&acc)[4][4], int wr, int wc, int lane) {
                 const int r0 = qt * 128 + wr + ((lane >> 4) << 2);
                 const int c0 = dt * 128 + wc + (lane & 15);
#pragma unroll
                 for (int i = 0; i < 4; ++i)
#pragma unroll
                   for (int j = 0; j < 4; ++j)
#pragma unroll
                     for (int rr = 0; rr < 4; ++rr)
                       Ob[(size_t)(r0 + i * 16 + rr) * 1024 + c0 + j * 16] =
                           acc[i][j][rr];
               });
}

extern "C" void kernel_launch(void* const* d_in, const int* in_sizes, int n_in,
                              void* d_out, int out_size, void* d_ws, size_t ws_size,
                              hipStream_t stream) {
  const float* x = (const float*)d_in[0];
  const float* Wq = (const float*)d_in[1];
  const float* bq = (const float*)d_in[2];
  const float* Wk = (const float*)d_in[3];
  const float* bk = (const float*)d_in[4];
  const float* Wv = (const float*)d_in[5];
  const float* bv = (const float*)d_in[6];
  float* out = (float*)d_out;
  char* ws = (char*)d_ws;
  u16* Qb = (u16*)(ws);
  u16* Kb = (u16*)(ws + (16u << 20));
  u16* Vtb = (u16*)(ws + (32u << 20));
  u16* xb = (u16*)(ws + (48u << 20));
  u16* Wcat = (u16*)(ws + (64u << 20));
  u16* S = (u16*)(ws + (70u << 20));
  u16* P = (u16*)(ws + (134u << 20));

  cvt_all_kernel<<<11264, 256, 0, stream>>>(x, Wq, Wk, Wv, xb, Wcat);
  qkv_qk_kernel<<<256, 512, 0, stream>>>(xb, Wcat, bq, bk, Qb, Kb);
  qkv_v_kernel<<<512, 256, 0, stream>>>(xb, Wcat, bv, Vtb);
  score_kernel<<<dim3(136, 4), 256, 0, stream>>>(Qb, Kb, S);
  softmax_kernel<<<8192, 256, 0, stream>>>(S, P);
  pv_kernel<<<512, 256, 0, stream>>>(P, Vtb, out);
}

// Round 10
// 149.311 us; speedup vs baseline: 1.4649x; 1.0878x over previous
//
#include <hip/hip_runtime.h>

// SelfAttention: B=4, T=2048, C=D=1024, causal, single head. bf16 MFMA.
// ws (MB): [0 Qb 16][16 Kb 16][32 Vtb 16][48 xb 16][64 Wcat 6][70 S bf16 32][134 P 32]
// R10: pv moved to BK=128 variant of the proven single-buffer template
// (halved barrier count; 64KB LDS; grid-limited 2 blocks/CU unchanged) with
// work-interleaved qt order (big/small mixed under any CU-assignment rule).
// score gets bijective XCD t-chunking (8x17). qkv_qk 8-phase, qkv_v, softmax,
// cvt unchanged from R9.

using u16 = unsigned short;
typedef __attribute__((ext_vector_type(8))) short short8;
typedef __attribute__((ext_vector_type(4))) float f32x4;

__device__ __forceinline__ u16 f2b(float f) {
  unsigned u = __builtin_bit_cast(unsigned, f);
  u += 0x7fffu + ((u >> 16) & 1u);
  return (u16)(u >> 16);
}

__device__ __forceinline__ float b2f(u16 h) {
  return __builtin_bit_cast(float, (unsigned)h << 16);
}

__device__ __forceinline__ void async16(void* lds, const void* g) {
  __builtin_amdgcn_global_load_lds(
      (const __attribute__((address_space(1))) unsigned int*)g,
      (__attribute__((address_space(3))) unsigned int*)lds, 16, 0, 0);
}

__device__ __forceinline__ void block_barrier() {
  asm volatile("" ::: "memory");
  __builtin_amdgcn_s_barrier();
  asm volatile("" ::: "memory");
}

// one launch: x (8192x1024) + Wq,Wk,Wv (1024x1024 each) -> bf16
__global__ __launch_bounds__(256) void cvt_all_kernel(
    const float* __restrict__ x, const float* __restrict__ Wq,
    const float* __restrict__ Wk, const float* __restrict__ Wv,
    u16* __restrict__ xb, u16* __restrict__ Wcat) {
  const int i = blockIdx.x * 256 + threadIdx.x;
  const float* src;
  u16* dst;
  int c;
  if (i < 2097152) {
    src = x; dst = xb; c = i;
  } else {
    const int r = i - 2097152;
    const int seg = r >> 18;
    src = seg == 0 ? Wq : (seg == 1 ? Wk : Wv);
    dst = Wcat + (size_t)seg * 1048576;
    c = r & 262143;
  }
  const float4 v = reinterpret_cast<const float4*>(src)[c];
  ushort4 o;
  o.x = f2b(v.x); o.y = f2b(v.y); o.z = f2b(v.z); o.w = f2b(v.w);
  reinterpret_cast<ushort4*>(dst)[c] = o;
}

// =================== 8-phase 256x256 BK=64 pipelined NT-GEMM ===============
#define STG_A(buf, half, roff, ku)                                          \
  {                                                                         \
    async16(&Asm[buf][half][tid * 8], gA0 + (size_t)(roff)*lda + (ku));     \
    async16(&Asm[buf][half][4096 + tid * 8],                                \
            gA0 + (size_t)((roff) + 128) * lda + (ku));                     \
  }
#define STG_B(buf, half, roff, ku)                                          \
  {                                                                         \
    async16(&Bsm[buf][half][tid * 8], gB0 + (size_t)(roff)*ldb + (ku));     \
    async16(&Bsm[buf][half][4096 + tid * 8],                                \
            gB0 + (size_t)((roff) + 128) * ldb + (ku));                     \
  }
#define RD_A(buf, hh)                                                       \
  {                                                                         \
    _Pragma("unroll") for (int ii = 0; ii < 4; ++ii) {                      \
      a[ii][0] = *(const short8*)(&Asm[buf][hh][aoff + ii * 1024 + sk0]);   \
      a[ii][1] = *(const short8*)(&Asm[buf][hh][aoff + ii * 1024 + sk1]);   \
    }                                                                       \
  }
#define RD_B(buf, cc, breg)                                                 \
  {                                                                         \
    _Pragma("unroll") for (int jj = 0; jj < 2; ++jj) {                      \
      breg[jj][0] = *(const short8*)(&Bsm[buf][cc][boff + jj * 1024 + sk0]);\
      breg[jj][1] = *(const short8*)(&Bsm[buf][cc][boff + jj * 1024 + sk1]);\
    }                                                                       \
  }
#define QUAD(hh, cc, breg)                                                  \
  {                                                                         \
    __builtin_amdgcn_s_setprio(1);                                          \
    _Pragma("unroll") for (int ii = 0; ii < 4; ++ii)                        \
        _Pragma("unroll") for (int jj = 0; jj < 2; ++jj) {                  \
      acc[(hh)*4 + ii][(cc)*2 + jj] =                                       \
          __builtin_amdgcn_mfma_f32_16x16x32_bf16(                          \
              a[ii][0], breg[jj][0], acc[(hh)*4 + ii][(cc)*2 + jj], 0,0,0); \
      acc[(hh)*4 + ii][(cc)*2 + jj] =                                       \
          __builtin_amdgcn_mfma_f32_16x16x32_bf16(                          \
              a[ii][1], breg[jj][1], acc[(hh)*4 + ii][(cc)*2 + jj], 0,0,0); \
    }                                                                       \
    __builtin_amdgcn_s_setprio(0);                                          \
  }
#define LGK0 asm volatile("s_waitcnt lgkmcnt(0)" ::: "memory")
#define VM6 asm volatile("s_waitcnt vmcnt(6)" ::: "memory")

template <int NT, typename Epi>
__device__ __forceinline__ void gemm256_8ph(const u16* __restrict__ A, int lda,
                                            const u16* __restrict__ B, int ldb,
                                            Epi&& epi) {
  __shared__ __align__(16) u16 Asm[2][2][8192];
  __shared__ __align__(16) u16 Bsm[2][2][8192];
  const int tid = threadIdx.x;  // 0..511
  const int lane = tid & 63;
  const int w = tid >> 6;
  const int wm = w >> 2;
  const int wn = w & 3;

  f32x4 acc[8][4];
#pragma unroll
  for (int i = 0; i < 8; ++i)
#pragma unroll
    for (int j = 0; j < 4; ++j) acc[i][j] = f32x4{0.f, 0.f, 0.f, 0.f};

  const int sr = tid >> 3;
  const int ce = ((tid & 7) ^ (sr & 7)) << 3;
  const u16* gA0 = A + (size_t)sr * lda + ce;
  const int bE = (sr & 31) + ((sr >> 5) << 6);
  const u16* gB0 = B + (size_t)bE * ldb + ce;

  const int l15 = lane & 15;
  const int hi = lane >> 4;
  const int lo7 = lane & 7;
  const int aoff = wm * 4096 + l15 * 64;
  const int boff = wn * 2048 + l15 * 64;
  const int sk0 = (hi ^ lo7) << 3;
  const int sk1 = ((4 + hi) ^ lo7) << 3;

  short8 a[4][2], bEr[2][2], bLr[2][2];

  STG_A(0, 0, 0, 0); STG_B(0, 0, 0, 0); STG_A(0, 1, 64, 0); STG_B(0, 1, 32, 0);
  STG_A(1, 0, 0, 64); STG_B(1, 0, 0, 64); STG_A(1, 1, 64, 64);
  VM6;
  block_barrier();

  for (int t = 0; t < NT; t += 2) {
    const int k1 = (t + 1) * 64;
    const int t2c = (t + 2 < NT) ? (t + 2) : (NT - 1);
    const int t3c = (t + 3 < NT) ? (t + 3) : (NT - 1);
    const int k2 = t2c * 64;
    const int k3 = t3c * 64;
    RD_A(0, 0); RD_B(0, 0, bEr); STG_B(1, 1, 32, k1);
    block_barrier(); LGK0; QUAD(0, 0, bEr); block_barrier();
    RD_B(0, 1, bLr); STG_A(0, 0, 0, k2);
    block_barrier(); LGK0; QUAD(0, 1, bLr); block_barrier();
    RD_A(0, 1); STG_B(0, 0, 0, k2);
    block_barrier(); LGK0; QUAD(1, 1, bLr); block_barrier();
    STG_A(0, 1, 64, k2);
    VM6; block_barrier(); QUAD(1, 0, bEr); block_barrier();
    RD_A(1, 0); RD_B(1, 0, bEr); STG_B(0, 1, 32, k2);
    block_barrier(); LGK0; QUAD(0, 0, bEr); block_barrier();
    RD_B(1, 1, bLr); STG_A(1, 0, 0, k3);
    block_barrier(); LGK0; QUAD(0, 1, bLr); block_barrier();
    RD_A(1, 1); STG_B(1, 0, 0, k3);
    block_barrier(); LGK0; QUAD(1, 1, bLr); block_barrier();
    STG_A(1, 1, 64, k3);
    VM6; block_barrier(); QUAD(1, 0, bEr); block_barrier();
  }
  asm volatile("s_waitcnt vmcnt(0)" ::: "memory");
  epi(acc, wm, wn, lane);
}

// Q+K projection: 256 blocks, XCD-swizzled.
__global__ __launch_bounds__(512, 1) void qkv_qk_kernel(
    const u16* __restrict__ xb, const u16* __restrict__ Wcat,
    const float* __restrict__ bq, const float* __restrict__ bk,
    u16* __restrict__ Qb, u16* __restrict__ Kb) {
  const int bid = blockIdx.x;
  const int swz = (bid & 7) * 32 + (bid >> 3);
  const int mt = swz >> 3, nt = swz & 7;
  const int z = nt >> 2;
  const float* bias = z ? bk : bq;
  u16* out = z ? Kb : Qb;
  const float scale = z ? 1.0f : 0.03125f;
  gemm256_8ph<16>(
      xb + (size_t)mt * 256 * 1024, 1024, Wcat + (size_t)nt * 256 * 1024, 1024,
      [&](f32x4(&acc)[8][4], int wm, int wn, int lane) {
        const int r0 = mt * 256 + wm * 128 + ((lane >> 4) << 2);
        const int c0 = (nt & 3) * 256 + wn * 64 + (lane & 15);
#pragma unroll
        for (int i8 = 0; i8 < 8; ++i8) {
          const int rb = r0 + (i8 >> 2) * 64 + (i8 & 3) * 16;
#pragma unroll
          for (int i4 = 0; i4 < 4; ++i4) {
            const int col = c0 + (i4 >> 1) * 32 + (i4 & 1) * 16;
            const float bb = bias[col];
#pragma unroll
            for (int rr = 0; rr < 4; ++rr)
              out[(size_t)(rb + rr) * 1024 + col] =
                  f2b((acc[i8][i4][rr] + bb) * scale);
          }
        }
      });
}

// ============== single-buffer 128x128 BK=64 template (proven) ==============
template <typename Epi>
__device__ __forceinline__ void gemm_bt_tile(const u16* __restrict__ A, int lda,
                                             const u16* __restrict__ B, int ldb,
                                             int nt, Epi&& epi) {
  __shared__ __align__(16) u16 As[128 * 64];
  __shared__ __align__(16) u16 Bs[128 * 64];
  const int tid = threadIdx.x;
  const int lane = tid & 63;
  const int w = tid >> 6;
  const int wr = (w >> 1) << 6;
  const int wc = (w & 1) << 6;

  f32x4 acc[4][4];
#pragma unroll
  for (int i = 0; i < 4; ++i)
#pragma unroll
    for (int j = 0; j < 4; ++j) acc[i][j] = f32x4{0.f, 0.f, 0.f, 0.f};

  const int sr = tid >> 3;
  const int ce = ((tid & 7) ^ (sr & 7)) << 3;
  const u16* gA = A + (size_t)sr * lda + ce;
  const u16* gB = B + (size_t)sr * ldb + ce;
  u16* const dA = As + tid * 8;
  u16* const dB = Bs + tid * 8;

  const int hi = lane >> 4;
  const int lo7 = lane & 7;
  const int ra = (wr + (lane & 15)) << 6;
  const int rb = (wc + (lane & 15)) << 6;
  const int sk0 = (hi ^ lo7) << 3;
  const int sk1 = ((4 + hi) ^ lo7) << 3;

  for (int t = 0; t < nt; ++t) {
    __syncthreads();
#pragma unroll
    for (int s = 0; s < 4; ++s) {
      async16(dA + s * 2048, gA + (size_t)(s * 32) * lda);
      async16(dB + s * 2048, gB + (size_t)(s * 32) * ldb);
    }
    gA += 64;
    gB += 64;
    __syncthreads();
#pragma unroll
    for (int kk = 0; kk < 2; ++kk) {
      const int sk = kk ? sk1 : sk0;
      short8 af[4], bf[4];
#pragma unroll
      for (int i = 0; i < 4; ++i)
        af[i] = *(const short8*)(As + ra + i * 1024 + sk);
#pragma unroll
      for (int j = 0; j < 4; ++j)
        bf[j] = *(const short8*)(Bs + rb + j * 1024 + sk);
#pragma unroll
      for (int i = 0; i < 4; ++i)
#pragma unroll
        for (int j = 0; j < 4; ++j)
          acc[i][j] = __builtin_amdgcn_mfma_f32_16x16x32_bf16(af[i], bf[j],
                                                              acc[i][j], 0, 0, 0);
    }
  }
  epi(acc, wr, wc, lane);
}

// ============== BK=128 single-buffer variant (pv) ==========================
// LDS As[2 kh][128r][64c]; same per-half swizzle; 64 MFMA per sync pair.
template <typename Epi>
__device__ __forceinline__ void gemm_bt_128k(const u16* __restrict__ A, int lda,
                                             const u16* __restrict__ B, int ldb,
                                             int nt, Epi&& epi) {
  __shared__ __align__(16) u16 As[2][128 * 64];
  __shared__ __align__(16) u16 Bs[2][128 * 64];
  const int tid = threadIdx.x;
  const int lane = tid & 63;
  const int w = tid >> 6;
  const int wr = (w >> 1) << 6;
  const int wc = (w & 1) << 6;

  f32x4 acc[4][4];
#pragma unroll
  for (int i = 0; i < 4; ++i)
#pragma unroll
    for (int j = 0; j < 4; ++j) acc[i][j] = f32x4{0.f, 0.f, 0.f, 0.f};

  const int sr = tid >> 3;
  const int ce = ((tid & 7) ^ (sr & 7)) << 3;
  const u16* gA = A + (size_t)sr * lda + ce;
  const u16* gB = B + (size_t)sr * ldb + ce;

  const int hi = lane >> 4;
  const int lo7 = lane & 7;
  const int ra = (wr + (lane & 15)) << 6;
  const int rb = (wc + (lane & 15)) << 6;
  const int sk0 = (hi ^ lo7) << 3;
  const int sk1 = ((4 + hi) ^ lo7) << 3;

  for (int t = 0; t < nt; ++t) {
    __syncthreads();
#pragma unroll
    for (int kh = 0; kh < 2; ++kh)
#pragma unroll
      for (int s = 0; s < 4; ++s) {
        async16(&As[kh][tid * 8 + s * 2048],
                gA + kh * 64 + (size_t)(s * 32) * lda);
        async16(&Bs[kh][tid * 8 + s * 2048],
                gB + kh * 64 + (size_t)(s * 32) * ldb);
      }
    gA += 128;
    gB += 128;
    __syncthreads();
#pragma unroll
    for (int kk = 0; kk < 4; ++kk) {
      const int kh = kk >> 1;
      const int sk = (kk & 1) ? sk1 : sk0;
      short8 af[4], bf[4];
#pragma unroll
      for (int i = 0; i < 4; ++i)
        af[i] = *(const short8*)(&As[kh][ra + i * 1024 + sk]);
#pragma unroll
      for (int j = 0; j < 4; ++j)
        bf[j] = *(const short8*)(&Bs[kh][rb + j * 1024 + sk]);
#pragma unroll
      for (int i = 0; i < 4; ++i)
#pragma unroll
        for (int j = 0; j < 4; ++j)
          acc[i][j] = __builtin_amdgcn_mfma_f32_16x16x32_bf16(af[i], bf[j],
                                                              acc[i][j], 0, 0, 0);
    }
  }
  epi(acc, wr, wc, lane);
}

// V projection: Vt = Wv @ x^T; 512 blocks (8 mt x 64 nt), nt-grouped per XCD.
__global__ __launch_bounds__(256) void qkv_v_kernel(
    const u16* __restrict__ xb, const u16* __restrict__ Wcat,
    const float* __restrict__ bv, u16* __restrict__ Vtb) {
  const int bid = blockIdx.x;
  const int u = bid >> 3;
  const int nt = (bid & 7) * 8 + (u >> 3);
  const int mt = u & 7;
  const u16* Wvb = Wcat + (size_t)2 * 1048576;
  gemm_bt_tile(
      Wvb + (size_t)mt * 128 * 1024, 1024, xb + (size_t)nt * 128 * 1024, 1024, 16,
      [&](f32x4(&acc)[4][4], int wr, int wc, int lane) {
        const int r0 = mt * 128 + wr + ((lane >> 4) << 2);
        const int c0 = nt * 128 + wc + (lane & 15);
#pragma unroll
        for (int i = 0; i < 4; ++i)
#pragma unroll
          for (int rr = 0; rr < 4; ++rr) {
            const int row = r0 + i * 16 + rr;
            const float bb = bv[row];
#pragma unroll
            for (int j = 0; j < 4; ++j)
              Vtb[(size_t)row * 8192 + c0 + j * 16] = f2b(acc[i][j][rr] + bb);
          }
      });
}

// lower-triangle tiles: grid (136,4); XCD t-chunking (136 = 8*17); S bf16.
__global__ __launch_bounds__(256) void score_kernel(const u16* __restrict__ Qb,
                                                    const u16* __restrict__ Kb,
                                                    u16* __restrict__ S) {
  const int b = blockIdx.y;
  const int traw = blockIdx.x;
  const int t = (traw & 7) * 17 + (traw >> 3);  // bijective XCD chunking
  int qt = 0;
  while ((qt + 1) * (qt + 2) / 2 <= t) ++qt;
  const int kt = t - (qt * (qt + 1)) / 2;
  const u16* A = Qb + ((size_t)b * 2048 + qt * 128) * 1024;
  const u16* Bp = Kb + ((size_t)b * 2048 + kt * 128) * 1024;
  u16* Sb = S + (size_t)b * 2048 * 2048;
  gemm_bt_tile(A, 1024, Bp, 1024, 16,
               [&](f32x4(&acc)[4][4], int wr, int wc, int lane) {
                 const int r0 = qt * 128 + wr + ((lane >> 4) << 2);
                 const int c0 = kt * 128 + wc + (lane & 15);
#pragma unroll
                 for (int i = 0; i < 4; ++i)
#pragma unroll
                   for (int j = 0; j < 4; ++j)
#pragma unroll
                     for (int rr = 0; rr < 4; ++rr)
                       Sb[(size_t)(r0 + i * 16 + rr) * 2048 + c0 + j * 16] =
                           f2b(acc[i][j][rr]);
               });
}

// one block per row; bf16 S in, bf16 P out; fully short8-vectorized.
__global__ __launch_bounds__(256) void softmax_kernel(const u16* __restrict__ S,
                                                      u16* __restrict__ P) {
  __shared__ float redm[4], reds[4];
  const int rowid = blockIdx.x;
  const int b = rowid >> 11;
  const int q = rowid & 2047;
  const u16* Srow = S + ((size_t)b * 2048 + q) * 2048;
  u16* Prow = P + ((size_t)b * 2048 + q) * 2048;
  const int L = q + 1;
  const int Lpad = ((q >> 7) + 1) << 7;
  const int tid = threadIdx.x;
  const int k0 = tid << 3;
  const bool active = k0 < Lpad;
  float v[8];
  float m = -1e30f;
  if (active) {
    const short8 s8 = *(const short8*)(Srow + k0);
#pragma unroll
    for (int j = 0; j < 8; ++j) {
      v[j] = (k0 + j < L) ? b2f((u16)s8[j]) : -1e30f;
      m = fmaxf(m, v[j]);
    }
  }
#pragma unroll
  for (int o = 32; o > 0; o >>= 1) m = fmaxf(m, __shfl_xor(m, o));
  if ((tid & 63) == 0) redm[tid >> 6] = m;
  __syncthreads();
  m = fmaxf(fmaxf(redm[0], redm[1]), fmaxf(redm[2], redm[3]));
  float s = 0.f;
  if (active) {
#pragma unroll
    for (int j = 0; j < 8; ++j) {
      const float e = (k0 + j < L) ? __expf(v[j] - m) : 0.f;
      v[j] = e;
      s += e;
    }
  }
#pragma unroll
  for (int o = 32; o > 0; o >>= 1) s += __shfl_xor(s, o);
  if ((tid & 63) == 0) reds[tid >> 6] = s;
  __syncthreads();
  s = reds[0] + reds[1] + reds[2] + reds[3];
  const float inv = 1.0f / s;
  if (active) {
    short8 o8;
#pragma unroll
    for (int j = 0; j < 8; ++j)
      o8[j] = (short)((k0 + j < L) ? f2b(v[j] * inv) : (u16)0);
    *(short8*)(Prow + k0) = o8;
  }
}

// O = P @ V using Vt[d][t]; BK=128, K truncated by causality (nt = qt+1).
// Block order interleaves big/small qt: g even -> qt=15-g/2, g odd -> (g-1)/2.
__global__ __launch_bounds__(256) void pv_kernel(const u16* __restrict__ P,
                                                 const u16* __restrict__ Vtb,
                                                 float* __restrict__ O) {
  const int bid = blockIdx.x;  // 512
  const int g = bid >> 5;      // 0..15
  const int qt = (g & 1) ? ((g - 1) >> 1) : (15 - (g >> 1));
  const int inner = bid & 31;
  const int b = inner >> 3;
  const int dt = inner & 7;
  const u16* A = P + (size_t)b * 2048 * 2048 + (size_t)qt * 128 * 2048;
  const u16* Bp = Vtb + (size_t)dt * 128 * 8192 + b * 2048;
  float* Ob = O + (size_t)b * 2048 * 1024;
  gemm_bt_128k(A, 2048, Bp, 8192, qt + 1,
               [&](f32x4(&acc)[4][4], int wr, int wc, int lane) {
                 const int r0 = qt * 128 + wr + ((lane >> 4) << 2);
                 const int c0 = dt * 128 + wc + (lane & 15);
#pragma unroll
                 for (int i = 0; i < 4; ++i)
#pragma unroll
                   for (int j = 0; j < 4; ++j)
#pragma unroll
                     for (int rr = 0; rr < 4; ++rr)
                       Ob[(size_t)(r0 + i * 16 + rr) * 1024 + c0 + j * 16] =
                           acc[i][j][rr];
               });
}

extern "C" void kernel_launch(void* const* d_in, const int* in_sizes, int n_in,
                              void* d_out, int out_size, void* d_ws, size_t ws_size,
                              hipStream_t stream) {
  const float* x = (const float*)d_in[0];
  const float* Wq = (const float*)d_in[1];
  const float* bq = (const float*)d_in[2];
  const float* Wk = (const float*)d_in[3];
  const float* bk = (const float*)d_in[4];
  const float* Wv = (const float*)d_in[5];
  const float* bv = (const float*)d_in[6];
  float* out = (float*)d_out;
  char* ws = (char*)d_ws;
  u16* Qb = (u16*)(ws);
  u16* Kb = (u16*)(ws + (16u << 20));
  u16* Vtb = (u16*)(ws + (32u << 20));
  u16* xb = (u16*)(ws + (48u << 20));
  u16* Wcat = (u16*)(ws + (64u << 20));
  u16* S = (u16*)(ws + (70u << 20));
  u16* P = (u16*)(ws + (134u << 20));

  cvt_all_kernel<<<11264, 256, 0, stream>>>(x, Wq, Wk, Wv, xb, Wcat);
  qkv_qk_kernel<<<256, 512, 0, stream>>>(xb, Wcat, bq, bk, Qb, Kb);
  qkv_v_kernel<<<512, 256, 0, stream>>>(xb, Wcat, bv, Vtb);
  score_kernel<<<dim3(136, 4), 256, 0, stream>>>(Qb, Kb, S);
  softmax_kernel<<<8192, 256, 0, stream>>>(S, P);
  pv_kernel<<<512, 256, 0, stream>>>(P, Vtb, out);
}